// Round 9
// baseline (136.790 us; speedup 1.0000x reference)
//
#include <hip/hip_runtime.h>
#include <math.h>

typedef __attribute__((ext_vector_type(4))) int i32x4;
typedef __attribute__((ext_vector_type(4))) float f32x4;

#define GLOAD_LDS16(g, l)                                          \
  __builtin_amdgcn_global_load_lds(                                \
      (const __attribute__((address_space(1))) void*)(g),          \
      (__attribute__((address_space(3))) void*)(l), 16, 0, 0)

// ---------------- weight quantization (merged: W1 blocks 0-255, W2 blocks 256-511) ----------
__global__ void kWabs(const float* __restrict__ w1, const float* __restrict__ w2,
                      double* __restrict__ part) {
  const bool second = blockIdx.x >= 256;
  const float* w = second ? w2 : w1;
  const int n = second ? 262144 : 524288;
  int t = (blockIdx.x & 255) * 256 + threadIdx.x;
  double s = 0.0;
  for (int i = t; i < n; i += 65536) s += (double)fabsf(w[i]);
#pragma unroll
  for (int m = 32; m >= 1; m >>= 1) s += __shfl_xor(s, m);
  __shared__ double sd[4];
  int lane = threadIdx.x & 63, wid = threadIdx.x >> 6;
  if (lane == 0) sd[wid] = s;
  __syncthreads();
  if (threadIdx.x == 0) part[blockIdx.x] = (sd[0] + sd[1]) + (sd[2] + sd[3]);
}

__global__ void kWfin(const double* __restrict__ part, float* __restrict__ wsv) {
  const double* p = part + blockIdx.x * 256;
  const double n = (blockIdx.x == 0) ? 524288.0 : 262144.0;
  double s = p[threadIdx.x];
#pragma unroll
  for (int m = 32; m >= 1; m >>= 1) s += __shfl_xor(s, m);
  __shared__ double sd[4];
  int lane = threadIdx.x & 63, wid = threadIdx.x >> 6;
  if (lane == 0) sd[wid] = s;
  __syncthreads();
  if (threadIdx.x == 0) {
    double tot = (sd[0] + sd[1]) + (sd[2] + sd[3]);
    wsv[blockIdx.x] = fmaxf((float)(tot / n), 1e-5f);  // = 1/scale_w
  }
}

__global__ void kWq(const float* __restrict__ w1, const float* __restrict__ w2,
                    const float* __restrict__ wsv,
                    char* __restrict__ wq1, char* __restrict__ wq2) {
  const bool second = blockIdx.x >= 2048;
  const float* w = second ? w2 : w1;
  char* wq = second ? wq2 : wq1;
  const float scale = 1.0f / wsv[second ? 1 : 0];
  int i = (second ? blockIdx.x - 2048 : blockIdx.x) * 256 + threadIdx.x;
  float q = fminf(fmaxf(rintf(w[i] * scale), -1.0f), 1.0f);
  wq[i] = (char)(int)q;
}

// ---------------- kFused1: RMSNorm+quant (phase A, LDS A-panel) + BitLinear GEMM1 -------
// 512 blocks x 512 thr, 1 block/CU (133 KB LDS). Phase A: 8 waves x 8 rows; lane reads 16
// contiguous f32 (lanes 0-31 prior | 32-63 evid), shfl-reduce, quantize -> ds_write_b128
// into XOR-swizzled 64KB A-panel (never touches HBM). Phase B: double-buffered B staging
// via global_load_lds + i8 MFMA; A-frags read from panel. Epilogue: ReLU+RMSNorm+requant.
__global__ __launch_bounds__(512, 1) void kFused1(
    const float* __restrict__ prior, const float* __restrict__ evid,
    const char* __restrict__ Wq, const float* __restrict__ biasG,
    const float* __restrict__ wS,
    char* __restrict__ XqOut, float* __restrict__ rActOut) {
  __shared__ __align__(16) char Ap[65536];  // 64 rows x 1024 i8, col^((row&7)<<4) swizzle
  __shared__ __align__(16) union {
    char B[2][32768];                                // B double buffer (512 x 64 i8 each)
    struct { float sq[64][8]; float mx[64][8]; } ep; // epilogue cross-wave row reduce
  } u;
  __shared__ float rowSc[64];   // amax/127 per row
  __shared__ float biasS[512];

  const int tid = threadIdx.x;
  const int lane = tid & 63;
  const int wn = tid >> 6;   // wave 0..7
  const int lr = lane & 15;
  const int kg = lane >> 4;  // 0..3
  const size_t row0 = (size_t)blockIdx.x * 64;

  biasS[tid] = biasG[tid];

  // ---- Phase A: per-row RMSNorm + absmax quant into Ap ----
  {
    const float* srcBase = (lane >= 32) ? evid : prior;
    const int lcol = (lane & 31) * 16;      // col within the 512-wide half
    const int ldsCol = lane * 16;           // global col = half*512 + lcol
    const float* sp = srcBase + (row0 + wn * 8) * 512 + lcol;
    f32x4 x0 = ((const f32x4*)sp)[0];
    f32x4 x1 = ((const f32x4*)sp)[1];
    f32x4 x2 = ((const f32x4*)sp)[2];
    f32x4 x3 = ((const f32x4*)sp)[3];
#pragma unroll
    for (int rr = 0; rr < 8; ++rr) {
      f32x4 y0, y1, y2, y3;
      if (rr < 7) {  // prefetch next row (in flight during reduce/quant)
        const float* np = srcBase + (row0 + wn * 8 + rr + 1) * 512 + lcol;
        y0 = ((const f32x4*)np)[0]; y1 = ((const f32x4*)np)[1];
        y2 = ((const f32x4*)np)[2]; y3 = ((const f32x4*)np)[3];
      }
      float ss = 0.f, mx = 0.f;
      f32x4 xs[4] = {x0, x1, x2, x3};
#pragma unroll
      for (int v = 0; v < 4; ++v)
#pragma unroll
        for (int i = 0; i < 4; ++i) { float f = xs[v][i]; ss += f * f; mx = fmaxf(mx, fabsf(f)); }
#pragma unroll
      for (int m = 32; m >= 1; m >>= 1) { ss += __shfl_xor(ss, m); mx = fmaxf(mx, __shfl_xor(mx, m)); }
      const float inv = 1.0f / sqrtf(ss * (1.0f / 1024.0f) + 1e-6f);
      const float amax = fmaxf(mx * inv, 1e-5f);
      const float s = 127.0f / amax;
      i32x4 q;
#pragma unroll
      for (int v = 0; v < 4; ++v) {
        int p = 0;
#pragma unroll
        for (int i = 0; i < 4; ++i) {
          int qi = (int)fminf(fmaxf(rintf(xs[v][i] * inv * s), -128.0f), 127.0f);
          p |= (qi & 255) << (8 * i);
        }
        q[v] = p;
      }
      const int r = wn * 8 + rr;
      *(i32x4*)&Ap[r * 1024 + (ldsCol ^ ((r & 7) << 4))] = q;
      if (lane == 0) rowSc[r] = amax / 127.0f;
      if (rr < 7) { x0 = y0; x1 = y1; x2 = y2; x3 = y3; }
    }
  }

  // ---- Phase B: K-loop, B double-buffered, A from panel ----
  i32x4 acc[4][4];
#pragma unroll
  for (int a = 0; a < 4; ++a)
#pragma unroll
    for (int b = 0; b < 4; ++b) acc[a][b] = (i32x4){0, 0, 0, 0};

  const int lrow = lane >> 2;       // row within a 16-row B chunk
  const int lkb = (lane & 3) * 16;  // 16B k-slice within a 64B row
  const char* gB[4];
#pragma unroll
  for (int r = 0; r < 4; ++r)
    gB[r] = Wq + ((wn * 4 + r) * 16 + lrow) * (size_t)1024 + lkb;

#define STAGEB(b, k0)                                                \
  do {                                                               \
    _Pragma("unroll")                                                \
    for (int r = 0; r < 4; ++r)                                      \
      GLOAD_LDS16(gB[r] + (k0), &u.B[b][(wn * 4 + r) * 1024]);       \
  } while (0)

  STAGEB(0, 0);
  __syncthreads();  // drains vmcnt(0) for B buf0 AND lgkmcnt for the A-panel ds_writes

  const int aswz = (lr & 7) << 4;  // (row&7)<<4 with row = fm*16+lr
#pragma unroll 2
  for (int kt = 0; kt < 16; ++kt) {
    const int cur = kt & 1;
    if (kt + 1 < 16) STAGEB(cur ^ 1, (kt + 1) * 64);  // prefetch BEFORE compute
    const int acol = (kt * 64 + kg * 16) ^ aswz;
    i32x4 af[4];
#pragma unroll
    for (int fm = 0; fm < 4; ++fm)
      af[fm] = *(const i32x4*)&Ap[(fm * 16 + lr) * 1024 + acol];
#pragma unroll
    for (int fn = 0; fn < 4; ++fn) {
      i32x4 bf = *(const i32x4*)&u.B[cur][(wn * 64 + fn * 16 + lr) * 64 + kg * 16];
#pragma unroll
      for (int fm = 0; fm < 4; ++fm)
        acc[fm][fn] = __builtin_amdgcn_mfma_i32_16x16x64_i8(af[fm], bf, acc[fm][fn], 0, 0, 0);
    }
    __syncthreads();  // prefetched buf ready; cur safe to overwrite
  }
#undef STAGEB

  // ---- epilogue: acc elem j -> row fm*16+kg*4+j, col wn*64+fn*16+lr ----
  const float wsv_ = wS[0];
  f32x4 fa[4][4];
#pragma unroll
  for (int fm = 0; fm < 4; ++fm) {
    float sc[4];
#pragma unroll
    for (int j = 0; j < 4; ++j) sc[j] = rowSc[fm * 16 + kg * 4 + j] * wsv_;
#pragma unroll
    for (int fn = 0; fn < 4; ++fn) {
      const float bb = biasS[wn * 64 + fn * 16 + lr];
#pragma unroll
      for (int j = 0; j < 4; ++j)
        fa[fm][fn][j] = fmaxf((float)acc[fm][fn][j] * sc[j] + bb, 0.0f);
    }
  }
#pragma unroll
  for (int fm = 0; fm < 4; ++fm)
#pragma unroll
    for (int j = 0; j < 4; ++j) {
      float ss = 0.f, mx = 0.f;
#pragma unroll
      for (int fn = 0; fn < 4; ++fn) { float h = fa[fm][fn][j]; ss += h * h; mx = fmaxf(mx, h); }
#pragma unroll
      for (int m = 8; m >= 1; m >>= 1) { ss += __shfl_xor(ss, m); mx = fmaxf(mx, __shfl_xor(mx, m)); }
      if (lr == 0) {
        int rl = fm * 16 + kg * 4 + j;
        u.ep.sq[rl][wn] = ss;
        u.ep.mx[rl][wn] = mx;
      }
    }
  __syncthreads();
#pragma unroll
  for (int fm = 0; fm < 4; ++fm)
#pragma unroll
    for (int j = 0; j < 4; ++j) {
      const int rl = fm * 16 + kg * 4 + j;
      float sst = 0.f, mxt = 0.f;
#pragma unroll
      for (int w = 0; w < 8; ++w) {
        sst += u.ep.sq[rl][w];
        mxt = fmaxf(mxt, u.ep.mx[rl][w]);
      }
      float inv = 1.0f / sqrtf(sst * (1.0f / 512.0f) + 1e-6f);
      float amax = fmaxf(mxt * inv, 1e-5f);
      float s = 127.0f / amax;
      if (lr == 0 && wn == 0) rActOut[row0 + rl] = amax / 127.0f;
#pragma unroll
      for (int fn = 0; fn < 4; ++fn) {
        float xn = fa[fm][fn][j] * inv;
        int qi = (int)fminf(fmaxf(rintf(xn * s), -128.0f), 127.0f);
        XqOut[(row0 + rl) * 512 + wn * 64 + fn * 16 + lr] = (char)qi;
      }
    }
}

// ---------------- GEMM2: i8 MFMA + sigmoid*prior + per-block col sums ----------------
__global__ __launch_bounds__(512, 4) void kGemm2(
    const char* __restrict__ Xq, const char* __restrict__ Wq,
    const float* __restrict__ biasG, const float* __restrict__ rAct,
    const float* __restrict__ wS, const float* __restrict__ prior,
    float* __restrict__ outUn, float* __restrict__ partG) {
  constexpr int KDIM = 512;
  struct Stage { char A[4096]; char B[32768]; };
  __shared__ __align__(16) Stage st[2];
  __shared__ float rowR[64];
  __shared__ float biasS[512];
  __shared__ float normPart[512];

  const int tid = threadIdx.x;
  const int lane = tid & 63;
  const int wn = tid >> 6;
  const int lr = lane & 15;
  const int kg = lane >> 4;
  const size_t row0 = (size_t)blockIdx.x * 64;

  if (tid < 64) rowR[tid] = rAct[row0 + tid];
  biasS[tid] = biasG[tid];

  i32x4 acc[4][4];
#pragma unroll
  for (int a = 0; a < 4; ++a)
#pragma unroll
    for (int b = 0; b < 4; ++b) acc[a][b] = (i32x4){0, 0, 0, 0};

  const int lrow = lane >> 2;
  const int lkb = (lane & 3) * 16;
  const char* gA = Xq + (row0 + (wn & 3) * 16 + lrow) * (size_t)KDIM + lkb;
  const char* gB[4];
#pragma unroll
  for (int r = 0; r < 4; ++r)
    gB[r] = Wq + ((wn * 4 + r) * 16 + lrow) * (size_t)KDIM + lkb;

#define STAGE(b, k0)                                                 \
  do {                                                               \
    if (wn < 4) GLOAD_LDS16(gA + (k0), &st[b].A[(wn & 3) * 1024]);   \
    _Pragma("unroll")                                                \
    for (int r = 0; r < 4; ++r)                                      \
      GLOAD_LDS16(gB[r] + (k0), &st[b].B[(wn * 4 + r) * 1024]);      \
  } while (0)

  constexpr int NT = KDIM / 64;
  STAGE(0, 0);
  __syncthreads();

#pragma unroll 2
  for (int kt = 0; kt < NT; ++kt) {
    const int cur = kt & 1;
    if (kt + 1 < NT) STAGE(cur ^ 1, (kt + 1) * 64);
    i32x4 af[4];
#pragma unroll
    for (int fm = 0; fm < 4; ++fm)
      af[fm] = *(const i32x4*)&st[cur].A[(fm * 16 + lr) * 64 + kg * 16];
#pragma unroll
    for (int fn = 0; fn < 4; ++fn) {
      i32x4 bf = *(const i32x4*)&st[cur].B[(wn * 64 + fn * 16 + lr) * 64 + kg * 16];
#pragma unroll
      for (int fm = 0; fm < 4; ++fm)
        acc[fm][fn] = __builtin_amdgcn_mfma_i32_16x16x64_i8(af[fm], bf, acc[fm][fn], 0, 0, 0);
    }
    __syncthreads();
  }
#undef STAGE

  const float wsv_ = wS[0];
  float colsum[4] = {0.f, 0.f, 0.f, 0.f};
#pragma unroll
  for (int fm = 0; fm < 4; ++fm) {
    float sc[4];
#pragma unroll
    for (int j = 0; j < 4; ++j) sc[j] = rowR[fm * 16 + kg * 4 + j] * wsv_;
#pragma unroll
    for (int fn = 0; fn < 4; ++fn) {
      const int col = wn * 64 + fn * 16 + lr;
      const float bb = biasS[col];
#pragma unroll
      for (int j = 0; j < 4; ++j) {
        const size_t rg = row0 + fm * 16 + kg * 4 + j;
        float v = (float)acc[fm][fn][j] * sc[j] + bb;
        float like = 1.0f / (1.0f + expf(-v));
        float un = prior[rg * 512 + col] * like;
        outUn[rg * 512 + col] = un;
        colsum[fn] += un;
      }
    }
  }
#pragma unroll
  for (int fn = 0; fn < 4; ++fn) {
    colsum[fn] += __shfl_xor(colsum[fn], 16);
    colsum[fn] += __shfl_xor(colsum[fn], 32);
  }
  if (lane < 16) {
#pragma unroll
    for (int fn = 0; fn < 4; ++fn) normPart[wn * 64 + fn * 16 + lane] = colsum[fn];
  }
  __syncthreads();
  partG[(size_t)blockIdx.x * 512 + tid] = normPart[tid];
}

// ---------------- normalization over S ----------------
__global__ void kNorm1(const float* __restrict__ partG, float* __restrict__ normA) {
  const int b = blockIdx.x, f = threadIdx.x;
  float s = 0.f;
#pragma unroll
  for (int i = 0; i < 16; ++i) s += partG[(size_t)(b * 16 + i) * 512 + f];
  normA[b * 512 + f] = fmaxf(s, 1e-10f);
}

__global__ void kNorm2(float* __restrict__ out, const float* __restrict__ normA) {
  const size_t i4 = (size_t)blockIdx.x * blockDim.x + threadIdx.x;
  f32x4 v = ((const f32x4*)out)[i4];
  const int f4 = (int)(i4 & 127);
  const int b = (int)(i4 >> 17);
  f32x4 n = ((const f32x4*)normA)[b * 128 + f4];
  v[0] /= n[0]; v[1] /= n[1]; v[2] /= n[2]; v[3] /= n[3];
  ((f32x4*)out)[i4] = v;
}

// ---------------- launcher ----------------
extern "C" void kernel_launch(void* const* d_in, const int* in_sizes, int n_in,
                              void* d_out, int out_size, void* d_ws, size_t ws_size,
                              hipStream_t stream) {
  const float* evid  = (const float*)d_in[0];   // [32,1024,512]
  const float* prior = (const float*)d_in[1];   // [32,1024,512]
  const float* W1    = (const float*)d_in[2];   // [512,1024]
  const float* b1    = (const float*)d_in[3];   // [512]
  const float* W2    = (const float*)d_in[4];   // [512,512]
  const float* b2    = (const float*)d_in[5];   // [512]
  float* out = (float*)d_out;

  char* ws = (char*)d_ws;
  char*   X2q   = ws;                              // 16,777,216 B (i8 [32768][512])
  char*   W1q   = ws + 16777216;                   //    524,288 B
  char*   W2q   = ws + 17301504;                   //    262,144 B
  float*  r2    = (float*)(ws + 17563648);         //    131,072 B
  double* part  = (double*)(ws + 17694720);        //      4,096 B
  float*  wsv   = (float*)(ws + 17698816);         //        256 B
  float*  partG = (float*)(ws + 17699072);         //  1,048,576 B
  float*  normA = (float*)(ws + 18747648);         //     65,536 B (total ~18.8 MB)

  kWabs<<<512, 256, 0, stream>>>(W1, W2, part);
  kWfin<<<2, 256, 0, stream>>>(part, wsv);
  kWq<<<3072, 256, 0, stream>>>(W1, W2, wsv, W1q, W2q);
  kFused1<<<512, 512, 0, stream>>>(prior, evid, W1q, b1, wsv + 0, X2q, r2);
  kGemm2<<<512, 512, 0, stream>>>(X2q, W2q, b2, r2, wsv + 1, prior, out, partG);
  kNorm1<<<32, 512, 0, stream>>>(partG, normA);
  kNorm2<<<16384, 256, 0, stream>>>(out, normA);
}

// Round 10
// 135.290 us; speedup vs baseline: 1.0111x; 1.0111x over previous
//
#include <hip/hip_runtime.h>
#include <math.h>

typedef __attribute__((ext_vector_type(4))) int i32x4;
typedef __attribute__((ext_vector_type(4))) float f32x4;

#define GLOAD_LDS16(g, l)                                          \
  __builtin_amdgcn_global_load_lds(                                \
      (const __attribute__((address_space(1))) void*)(g),          \
      (__attribute__((address_space(3))) void*)(l), 16, 0, 0)

// ---------------- weight quantization (merged: W1 blocks 0-255, W2 blocks 256-511) ----------
__global__ void kWabs(const float* __restrict__ w1, const float* __restrict__ w2,
                      double* __restrict__ part) {
  const bool second = blockIdx.x >= 256;
  const float* w = second ? w2 : w1;
  const int n = second ? 262144 : 524288;
  int t = (blockIdx.x & 255) * 256 + threadIdx.x;
  double s = 0.0;
  for (int i = t; i < n; i += 65536) s += (double)fabsf(w[i]);
#pragma unroll
  for (int m = 32; m >= 1; m >>= 1) s += __shfl_xor(s, m);
  __shared__ double sd[4];
  int lane = threadIdx.x & 63, wid = threadIdx.x >> 6;
  if (lane == 0) sd[wid] = s;
  __syncthreads();
  if (threadIdx.x == 0) part[blockIdx.x] = (sd[0] + sd[1]) + (sd[2] + sd[3]);
}

__global__ void kWfin(const double* __restrict__ part, float* __restrict__ wsv) {
  const double* p = part + blockIdx.x * 256;
  const double n = (blockIdx.x == 0) ? 524288.0 : 262144.0;
  double s = p[threadIdx.x];
#pragma unroll
  for (int m = 32; m >= 1; m >>= 1) s += __shfl_xor(s, m);
  __shared__ double sd[4];
  int lane = threadIdx.x & 63, wid = threadIdx.x >> 6;
  if (lane == 0) sd[wid] = s;
  __syncthreads();
  if (threadIdx.x == 0) {
    double tot = (sd[0] + sd[1]) + (sd[2] + sd[3]);
    wsv[blockIdx.x] = fmaxf((float)(tot / n), 1e-5f);  // = 1/scale_w
  }
}

__global__ void kWq(const float* __restrict__ w1, const float* __restrict__ w2,
                    const float* __restrict__ wsv,
                    char* __restrict__ wq1, char* __restrict__ wq2) {
  const bool second = blockIdx.x >= 2048;
  const float* w = second ? w2 : w1;
  char* wq = second ? wq2 : wq1;
  const float scale = 1.0f / wsv[second ? 1 : 0];
  int i = (second ? blockIdx.x - 2048 : blockIdx.x) * 256 + threadIdx.x;
  float q = fminf(fmaxf(rintf(w[i] * scale), -1.0f), 1.0f);
  wq[i] = (char)(int)q;
}

// ---------------- kFused1: RMSNorm+quant (LDS A-panel) + BitLinear GEMM1 -------------
// 512 blocks x 512 thr, 2 blocks/CU (68 KB LDS). Phase A: 8 waves x 8 rows, quantize into
// XOR-swizzled A-panel. Phase B: barrier-free K-loop — B fragments loaded global->reg
// (W1q is L2-resident), A-frags from panel. Epilogue: ReLU + row-RMSNorm + requant.
__global__ __launch_bounds__(512, 4) void kFused1(
    const float* __restrict__ prior, const float* __restrict__ evid,
    const char* __restrict__ Wq, const float* __restrict__ biasG,
    const float* __restrict__ wS,
    char* __restrict__ XqOut, float* __restrict__ rActOut) {
  __shared__ __align__(16) union {
    char Ap[65536];                                  // 64 rows x 1024 i8, col^((r&7)<<4)
    struct { float sq[64][8]; float mx[64][8]; } ep; // epilogue overlay (post-barrier)
  } u;
  __shared__ float rowSc[64];
  __shared__ float biasS[512];

  const int tid = threadIdx.x;
  const int lane = tid & 63;
  const int wn = tid >> 6;   // wave 0..7
  const int lr = lane & 15;
  const int kg = lane >> 4;  // 0..3
  const size_t row0 = (size_t)blockIdx.x * 64;

  biasS[tid] = biasG[tid];

  // ---- Phase A: per-row RMSNorm + absmax quant into Ap ----
  {
    const float* srcBase = (lane >= 32) ? evid : prior;
    const int lcol = (lane & 31) * 16;
    const int ldsCol = lane * 16;
    const float* sp = srcBase + (row0 + wn * 8) * 512 + lcol;
    f32x4 x0 = ((const f32x4*)sp)[0];
    f32x4 x1 = ((const f32x4*)sp)[1];
    f32x4 x2 = ((const f32x4*)sp)[2];
    f32x4 x3 = ((const f32x4*)sp)[3];
#pragma unroll
    for (int rr = 0; rr < 8; ++rr) {
      f32x4 y0, y1, y2, y3;
      if (rr < 7) {
        const float* np = srcBase + (row0 + wn * 8 + rr + 1) * 512 + lcol;
        y0 = ((const f32x4*)np)[0]; y1 = ((const f32x4*)np)[1];
        y2 = ((const f32x4*)np)[2]; y3 = ((const f32x4*)np)[3];
      }
      float ss = 0.f, mx = 0.f;
      f32x4 xs[4] = {x0, x1, x2, x3};
#pragma unroll
      for (int v = 0; v < 4; ++v)
#pragma unroll
        for (int i = 0; i < 4; ++i) { float f = xs[v][i]; ss += f * f; mx = fmaxf(mx, fabsf(f)); }
#pragma unroll
      for (int m = 32; m >= 1; m >>= 1) { ss += __shfl_xor(ss, m); mx = fmaxf(mx, __shfl_xor(mx, m)); }
      const float inv = 1.0f / sqrtf(ss * (1.0f / 1024.0f) + 1e-6f);
      const float amax = fmaxf(mx * inv, 1e-5f);
      const float s = 127.0f / amax;
      i32x4 q;
#pragma unroll
      for (int v = 0; v < 4; ++v) {
        int p = 0;
#pragma unroll
        for (int i = 0; i < 4; ++i) {
          int qi = (int)fminf(fmaxf(rintf(xs[v][i] * inv * s), -128.0f), 127.0f);
          p |= (qi & 255) << (8 * i);
        }
        q[v] = p;
      }
      const int r = wn * 8 + rr;
      *(i32x4*)&u.Ap[r * 1024 + (ldsCol ^ ((r & 7) << 4))] = q;
      if (lane == 0) rowSc[r] = amax / 127.0f;
      if (rr < 7) { x0 = y0; x1 = y1; x2 = y2; x3 = y3; }
    }
  }

  // ---- Phase B: barrier-free K-loop, B global->reg, A from panel ----
  i32x4 acc[4][4];
#pragma unroll
  for (int a = 0; a < 4; ++a)
#pragma unroll
    for (int b = 0; b < 4; ++b) acc[a][b] = (i32x4){0, 0, 0, 0};

  const char* gBl = Wq + (size_t)(wn * 64 + lr) * 1024 + kg * 16;
  i32x4 bf[4];
#pragma unroll
  for (int fn = 0; fn < 4; ++fn)
    bf[fn] = *(const i32x4*)(gBl + fn * 16384);  // issue before barrier: overlaps wait

  __syncthreads();  // A-panel ds_writes visible to all waves

  const int aswz = (lr & 7) << 4;
#pragma unroll 2
  for (int kt = 0; kt < 16; ++kt) {
    i32x4 bn[4];
    if (kt < 15) {
#pragma unroll
      for (int fn = 0; fn < 4; ++fn)
        bn[fn] = *(const i32x4*)(gBl + (kt + 1) * 64 + fn * 16384);
    }
    const int acol = (kt * 64 + kg * 16) ^ aswz;
    i32x4 af[4];
#pragma unroll
    for (int fm = 0; fm < 4; ++fm)
      af[fm] = *(const i32x4*)&u.Ap[(fm * 16 + lr) * 1024 + acol];
#pragma unroll
    for (int fn = 0; fn < 4; ++fn)
#pragma unroll
      for (int fm = 0; fm < 4; ++fm)
        acc[fm][fn] = __builtin_amdgcn_mfma_i32_16x16x64_i8(af[fm], bf[fn], acc[fm][fn], 0, 0, 0);
#pragma unroll
    for (int fn = 0; fn < 4; ++fn) bf[fn] = bn[fn];
  }

  __syncthreads();  // all Ap reads done: safe to overlay u.ep

  // ---- epilogue: acc elem j -> row fm*16+kg*4+j, col wn*64+fn*16+lr ----
  const float wsv_ = wS[0];
  f32x4 fa[4][4];
#pragma unroll
  for (int fm = 0; fm < 4; ++fm) {
    float sc[4];
#pragma unroll
    for (int j = 0; j < 4; ++j) sc[j] = rowSc[fm * 16 + kg * 4 + j] * wsv_;
#pragma unroll
    for (int fn = 0; fn < 4; ++fn) {
      const float bb = biasS[wn * 64 + fn * 16 + lr];
#pragma unroll
      for (int j = 0; j < 4; ++j)
        fa[fm][fn][j] = fmaxf((float)acc[fm][fn][j] * sc[j] + bb, 0.0f);
    }
  }
#pragma unroll
  for (int fm = 0; fm < 4; ++fm)
#pragma unroll
    for (int j = 0; j < 4; ++j) {
      float ss = 0.f, mx = 0.f;
#pragma unroll
      for (int fn = 0; fn < 4; ++fn) { float h = fa[fm][fn][j]; ss += h * h; mx = fmaxf(mx, h); }
#pragma unroll
      for (int m = 8; m >= 1; m >>= 1) { ss += __shfl_xor(ss, m); mx = fmaxf(mx, __shfl_xor(mx, m)); }
      if (lr == 0) {
        int rl = fm * 16 + kg * 4 + j;
        u.ep.sq[rl][wn] = ss;
        u.ep.mx[rl][wn] = mx;
      }
    }
  __syncthreads();
#pragma unroll
  for (int fm = 0; fm < 4; ++fm)
#pragma unroll
    for (int j = 0; j < 4; ++j) {
      const int rl = fm * 16 + kg * 4 + j;
      float sst = 0.f, mxt = 0.f;
#pragma unroll
      for (int w = 0; w < 8; ++w) {
        sst += u.ep.sq[rl][w];
        mxt = fmaxf(mxt, u.ep.mx[rl][w]);
      }
      float inv = 1.0f / sqrtf(sst * (1.0f / 512.0f) + 1e-6f);
      float amax = fmaxf(mxt * inv, 1e-5f);
      float s = 127.0f / amax;
      if (lr == 0 && wn == 0) rActOut[row0 + rl] = amax / 127.0f;
#pragma unroll
      for (int fn = 0; fn < 4; ++fn) {
        float xn = fa[fm][fn][j] * inv;
        int qi = (int)fminf(fmaxf(rintf(xn * s), -128.0f), 127.0f);
        XqOut[(row0 + rl) * 512 + wn * 64 + fn * 16 + lr] = (char)qi;
      }
    }
}

// ---------------- GEMM2: whole-A staged once (pre-swizzled source), barrier-free K-loop,
//                  B global->reg; epilogue: sigmoid * prior + per-block col sums --------
__global__ __launch_bounds__(512, 4) void kGemm2(
    const char* __restrict__ Xq, const char* __restrict__ Wq,
    const float* __restrict__ biasG, const float* __restrict__ rAct,
    const float* __restrict__ wS, const float* __restrict__ prior,
    float* __restrict__ outUn, float* __restrict__ partG) {
  __shared__ __align__(16) char A[32768];  // [64][512] i8, col^((r&7)<<4)
  __shared__ float rowR[64];
  __shared__ float biasS[512];
  __shared__ float normPart[512];

  const int tid = threadIdx.x;
  const int lane = tid & 63;
  const int wn = tid >> 6;
  const int lr = lane & 15;
  const int kg = lane >> 4;
  const size_t row0 = (size_t)blockIdx.x * 64;

  if (tid < 64) rowR[tid] = rAct[row0 + tid];
  biasS[tid] = biasG[tid];

  // stage whole 64x512 A-tile: linear LDS dest, XOR-swizzled global source (m173 pattern)
#pragma unroll
  for (int i = 0; i < 4; ++i) {
    const int r = i * 16 + wn * 2 + (lane >> 5);
    const int cs = ((lane & 31) * 16) ^ ((r & 7) << 4);
    GLOAD_LDS16(Xq + (row0 + r) * 512 + cs, &A[i * 8192 + wn * 1024]);
  }

  const char* gBl = Wq + (size_t)(wn * 64 + lr) * 512 + kg * 16;
  i32x4 bf[4];
#pragma unroll
  for (int fn = 0; fn < 4; ++fn)
    bf[fn] = *(const i32x4*)(gBl + fn * 8192);

  i32x4 acc[4][4];
#pragma unroll
  for (int a = 0; a < 4; ++a)
#pragma unroll
    for (int b = 0; b < 4; ++b) acc[a][b] = (i32x4){0, 0, 0, 0};

  __syncthreads();  // A staged (implicit vmcnt(0) drain covers global_load_lds)

  const int aswz = (lr & 7) << 4;
#pragma unroll 2
  for (int kt = 0; kt < 8; ++kt) {
    i32x4 bn[4];
    if (kt < 7) {
#pragma unroll
      for (int fn = 0; fn < 4; ++fn)
        bn[fn] = *(const i32x4*)(gBl + (kt + 1) * 64 + fn * 8192);
    }
    const int acol = (kt * 64 + kg * 16) ^ aswz;
    i32x4 af[4];
#pragma unroll
    for (int fm = 0; fm < 4; ++fm)
      af[fm] = *(const i32x4*)&A[(fm * 16 + lr) * 512 + acol];
#pragma unroll
    for (int fn = 0; fn < 4; ++fn)
#pragma unroll
      for (int fm = 0; fm < 4; ++fm)
        acc[fm][fn] = __builtin_amdgcn_mfma_i32_16x16x64_i8(af[fm], bf[fn], acc[fm][fn], 0, 0, 0);
#pragma unroll
    for (int fn = 0; fn < 4; ++fn) bf[fn] = bn[fn];
  }

  // ---- epilogue ----
  const float wsv_ = wS[0];
  float colsum[4] = {0.f, 0.f, 0.f, 0.f};
#pragma unroll
  for (int fm = 0; fm < 4; ++fm) {
    float sc[4];
#pragma unroll
    for (int j = 0; j < 4; ++j) sc[j] = rowR[fm * 16 + kg * 4 + j] * wsv_;
#pragma unroll
    for (int fn = 0; fn < 4; ++fn) {
      const int col = wn * 64 + fn * 16 + lr;
      const float bb = biasS[col];
#pragma unroll
      for (int j = 0; j < 4; ++j) {
        const size_t rg = row0 + fm * 16 + kg * 4 + j;
        float v = (float)acc[fm][fn][j] * sc[j] + bb;
        float like = 1.0f / (1.0f + expf(-v));
        float un = prior[rg * 512 + col] * like;
        outUn[rg * 512 + col] = un;
        colsum[fn] += un;
      }
    }
  }
#pragma unroll
  for (int fn = 0; fn < 4; ++fn) {
    colsum[fn] += __shfl_xor(colsum[fn], 16);
    colsum[fn] += __shfl_xor(colsum[fn], 32);
  }
  if (lane < 16) {
#pragma unroll
    for (int fn = 0; fn < 4; ++fn) normPart[wn * 64 + fn * 16 + lane] = colsum[fn];
  }
  __syncthreads();
  partG[(size_t)blockIdx.x * 512 + tid] = normPart[tid];
}

// ---------------- normalization over S ----------------
__global__ void kNorm1(const float* __restrict__ partG, float* __restrict__ normA) {
  const int b = blockIdx.x, f = threadIdx.x;
  float s = 0.f;
#pragma unroll
  for (int i = 0; i < 16; ++i) s += partG[(size_t)(b * 16 + i) * 512 + f];
  normA[b * 512 + f] = fmaxf(s, 1e-10f);
}

__global__ void kNorm2(float* __restrict__ out, const float* __restrict__ normA) {
  const size_t i4 = (size_t)blockIdx.x * blockDim.x + threadIdx.x;
  f32x4 v = ((const f32x4*)out)[i4];
  const int f4 = (int)(i4 & 127);
  const int b = (int)(i4 >> 17);
  f32x4 n = ((const f32x4*)normA)[b * 128 + f4];
  v[0] /= n[0]; v[1] /= n[1]; v[2] /= n[2]; v[3] /= n[3];
  ((f32x4*)out)[i4] = v;
}

// ---------------- launcher ----------------
extern "C" void kernel_launch(void* const* d_in, const int* in_sizes, int n_in,
                              void* d_out, int out_size, void* d_ws, size_t ws_size,
                              hipStream_t stream) {
  const float* evid  = (const float*)d_in[0];   // [32,1024,512]
  const float* prior = (const float*)d_in[1];   // [32,1024,512]
  const float* W1    = (const float*)d_in[2];   // [512,1024]
  const float* b1    = (const float*)d_in[3];   // [512]
  const float* W2    = (const float*)d_in[4];   // [512,512]
  const float* b2    = (const float*)d_in[5];   // [512]
  float* out = (float*)d_out;

  char* ws = (char*)d_ws;
  char*   X2q   = ws;                              // 16,777,216 B (i8 [32768][512])
  char*   W1q   = ws + 16777216;                   //    524,288 B
  char*   W2q   = ws + 17301504;                   //    262,144 B
  float*  r2    = (float*)(ws + 17563648);         //    131,072 B
  double* part  = (double*)(ws + 17694720);        //      4,096 B
  float*  wsv   = (float*)(ws + 17698816);         //        256 B
  float*  partG = (float*)(ws + 17699072);         //  1,048,576 B
  float*  normA = (float*)(ws + 18747648);         //     65,536 B (total ~18.8 MB)

  kWabs<<<512, 256, 0, stream>>>(W1, W2, part);
  kWfin<<<2, 256, 0, stream>>>(part, wsv);
  kWq<<<3072, 256, 0, stream>>>(W1, W2, wsv, W1q, W2q);
  kFused1<<<512, 512, 0, stream>>>(prior, evid, W1q, b1, wsv + 0, X2q, r2);
  kGemm2<<<512, 512, 0, stream>>>(X2q, W2q, b2, r2, wsv + 1, prior, out, partG);
  kNorm1<<<32, 512, 0, stream>>>(partG, normA);
  kNorm2<<<16384, 256, 0, stream>>>(out, normA);
}